// Round 1
// baseline (312.075 us; speedup 1.0000x reference)
//
#include <hip/hip_runtime.h>

// Problem constants (match reference)
#define NUM_P      16
#define STEP       4
#define NUM_BLOCKS 256   // blocks per permutation (DIM / STEP)
#define DIM        1024
#define BATCH      4096

// Kernel A: extract the block permutation from the dense T matrices.
// T[p, 4r, 4c] == 1.0 exactly when permutation p maps block-row r to
// block-col c. One thread per (p, r, c) candidate; exactly one thread
// per (p, r) sees a nonzero and writes.
__global__ __launch_bounds__(256) void extract_perm_kernel(
    const float* __restrict__ T, int* __restrict__ perm) {
    int idx = blockIdx.x * blockDim.x + threadIdx.x;  // p*65536 + r*256 + c
    int c = idx & (NUM_BLOCKS - 1);
    int r = (idx >> 8) & (NUM_BLOCKS - 1);
    int p = idx >> 16;
    // element T[p][4r][4c]
    size_t off = (size_t)p * DIM * DIM + (size_t)(STEP * r) * DIM + STEP * c;
    float v = T[off];
    if (v != 0.0f) {
        perm[p * NUM_BLOCKS + r] = c;
    }
}

// Kernel B: the gather. out[(i*BATCH + b)*DIM + 4j + k] = x[b*DIM + 4*perm[indices[i]][j] + k]
// Viewed as float4: out4[i*BATCH*256 + b*256 + j] = x4[b*256 + perm[indices[i]][j]]
__global__ __launch_bounds__(256) void gather_kernel(
    const float4* __restrict__ x4,
    const int* __restrict__ perm,
    const int* __restrict__ indices,
    float4* __restrict__ out4) {
    int idx = blockIdx.x * blockDim.x + threadIdx.x;
    int j = idx & (NUM_BLOCKS - 1);          // block-row within D (0..255)
    int b = (idx >> 8) & (BATCH - 1);        // batch row (0..4095)
    int i = idx >> 20;                       // output row-group (0..15)
    int p = indices[i];                      // wave-uniform within a block
    int c = perm[p * NUM_BLOCKS + j];        // coalesced int read
    out4[idx] = x4[(size_t)b * NUM_BLOCKS + c];
}

extern "C" void kernel_launch(void* const* d_in, const int* in_sizes, int n_in,
                              void* d_out, int out_size, void* d_ws, size_t ws_size,
                              hipStream_t stream) {
    const float* x       = (const float*)d_in[0];   // [BATCH, DIM] fp32
    const float* T       = (const float*)d_in[1];   // [NUM_P, DIM, DIM] fp32
    const int*   indices = (const int*)d_in[2];     // [NUM_P] int32
    float* out = (float*)d_out;                     // [NUM_P*BATCH, DIM] fp32

    int* perm = (int*)d_ws;                         // NUM_P * NUM_BLOCKS ints (16 KiB)

    // Kernel A: 16*256*256 = 1,048,576 threads
    {
        int total = NUM_P * NUM_BLOCKS * NUM_BLOCKS;
        dim3 block(256);
        dim3 grid(total / 256);
        extract_perm_kernel<<<grid, block, 0, stream>>>(T, perm);
    }

    // Kernel B: 16 * 4096 * 256 = 16,777,216 float4 threads
    {
        int total = NUM_P * BATCH * NUM_BLOCKS;
        dim3 block(256);
        dim3 grid(total / 256);
        gather_kernel<<<grid, block, 0, stream>>>(
            (const float4*)x, perm, indices, (float4*)out);
    }
    (void)in_sizes; (void)n_in; (void)out_size; (void)ws_size;
}